// Round 6
// baseline (3760.649 us; speedup 1.0000x reference)
//
#include <hip/hip_runtime.h>
#include <math.h>

#define DIV_UP(a,b) (((a)+(b)-1)/(b))

typedef __bf16 bf16x8 __attribute__((ext_vector_type(8)));
typedef float floatx4 __attribute__((ext_vector_type(4)));
typedef unsigned short u16;

__device__ __forceinline__ u16 f2bf(float f) {
    unsigned u = __builtin_bit_cast(unsigned, f);
    u = (u + 0x7fffu + ((u >> 16) & 1u)) >> 16;
    return (u16)u;
}
__device__ __forceinline__ float bf2f(u16 h) {
    unsigned u = ((unsigned)h) << 16;
    return __builtin_bit_cast(float, u);
}

// async global->LDS, 16B per lane (dest = wave-uniform base + lane*16; global addr per-lane)
__device__ __forceinline__ void gll16(const void* g, void* l) {
    __builtin_amdgcn_global_load_lds(
        (const __attribute__((address_space(1))) void*)g,
        (__attribute__((address_space(3))) void*)l, 16, 0, 0);
}

// ---------------------------------------------------------------------------
// Split-bf16 NT GEMM (fp32-accurate): C = alpha*sum_k A[m][k]*B[n][k] + epi.
// 2-phase double-buffered pipeline with counted vmcnt. (attention phase)
// ---------------------------------------------------------------------------
template<int BM, int BN, int GWM, int GWN>
__global__ __launch_bounds__(256) void gemm3_nt(
    const u16* __restrict__ Ah, const u16* __restrict__ Al,
    int lda, long long a_bs,
    const u16* __restrict__ Bh, const u16* __restrict__ Bl,
    int ldb, long long b_bs,
    float* C, u16* Ch, u16* Cl, int ldc, long long c_bs,
    const float* resid, int M, int N, int K, float alpha,
    const float* __restrict__ bias_m, const float* __restrict__ scale_m,
    const float* __restrict__ bias_n, int relu)
{
    constexpr int WTM = BM / GWM, WTN = BN / GWN;
    constexpr int TM = WTM / 16, TN = WTN / 16;
    constexpr int NLD = (BM / 64) * 2 + (BN / 64) * 2;  // gll16 per thread per tile
    __shared__ u16 Ash[2][BM * 32];
    __shared__ u16 Asl[2][BM * 32];
    __shared__ u16 Bsh[2][BN * 32];
    __shared__ u16 Bsl[2][BN * 32];
    const int tid = threadIdx.x;
    const int lane = tid & 63;
    const int w = tid >> 6;
    const int wm = (w % GWM) * WTM, wn = (w / GWM) * WTN;
    const int m0 = blockIdx.y * BM, n0 = blockIdx.x * BN;
    const int z = blockIdx.z;
    const u16* Ahb = Ah + (long long)z * a_bs;
    const u16* Alb = Al + (long long)z * a_bs;
    const u16* Bhb = Bh + (long long)z * b_bs;
    const u16* Blb = Bl + (long long)z * b_bs;
    const int quad = lane >> 4;

    floatx4 acc[TM][TN];
    #pragma unroll
    for (int i = 0; i < TM; ++i)
        #pragma unroll
        for (int j = 0; j < TN; ++j)
            #pragma unroll
            for (int r = 0; r < 4; ++r) acc[i][j][r] = 0.f;

    auto stage = [&](int kt, int buf) {
        #pragma unroll
        for (int p = 0; p < BM / 64; ++p) {
            int idx = p * 256 + tid;
            int row = idx >> 2;
            int olog = (idx & 3) ^ ((row >> 1) & 3);
            int gr = m0 + row; if (gr > M - 1) gr = M - 1;
            long long go = (long long)gr * lda + kt + olog * 8;
            gll16(Ahb + go, &Ash[buf][idx * 8]);
            gll16(Alb + go, &Asl[buf][idx * 8]);
        }
        #pragma unroll
        for (int p = 0; p < BN / 64; ++p) {
            int idx = p * 256 + tid;
            int row = idx >> 2;
            int olog = (idx & 3) ^ ((row >> 1) & 3);
            int gr = n0 + row; if (gr > N - 1) gr = N - 1;
            long long go = (long long)gr * ldb + kt + olog * 8;
            gll16(Bhb + go, &Bsh[buf][idx * 8]);
            gll16(Blb + go, &Bsl[buf][idx * 8]);
        }
    };

    stage(0, 0);
    int cur = 0;
    for (int kt = 0; kt < K; kt += 32) {
        if (kt + 32 < K) {
            stage(kt + 32, cur ^ 1);
            asm volatile("s_waitcnt vmcnt(%0)" :: "n"(NLD) : "memory");
        } else {
            asm volatile("s_waitcnt vmcnt(0)" ::: "memory");
        }
        __builtin_amdgcn_s_barrier();
        asm volatile("" ::: "memory");

        bf16x8 afh[TM], afl[TM], bfh[TN], bfl[TN];
        #pragma unroll
        for (int i = 0; i < TM; ++i) {
            int row = wm + i * 16 + (lane & 15);
            int oph = quad ^ ((row >> 1) & 3);
            afh[i] = *(const bf16x8*)&Ash[cur][row * 32 + oph * 8];
            afl[i] = *(const bf16x8*)&Asl[cur][row * 32 + oph * 8];
        }
        #pragma unroll
        for (int j = 0; j < TN; ++j) {
            int row = wn + j * 16 + (lane & 15);
            int oph = quad ^ ((row >> 1) & 3);
            bfh[j] = *(const bf16x8*)&Bsh[cur][row * 32 + oph * 8];
            bfl[j] = *(const bf16x8*)&Bsl[cur][row * 32 + oph * 8];
        }
        #pragma unroll
        for (int i = 0; i < TM; ++i)
            #pragma unroll
            for (int j = 0; j < TN; ++j) {
                acc[i][j] = __builtin_amdgcn_mfma_f32_16x16x32_bf16(afh[i], bfl[j], acc[i][j], 0, 0, 0);
                acc[i][j] = __builtin_amdgcn_mfma_f32_16x16x32_bf16(afl[i], bfh[j], acc[i][j], 0, 0, 0);
                acc[i][j] = __builtin_amdgcn_mfma_f32_16x16x32_bf16(afh[i], bfh[j], acc[i][j], 0, 0, 0);
            }

        asm volatile("s_waitcnt lgkmcnt(0)" ::: "memory");
        __builtin_amdgcn_s_barrier();
        cur ^= 1;
    }

    #pragma unroll
    for (int i = 0; i < TM; ++i) {
        int mbase = m0 + wm + i * 16 + quad * 4;
        #pragma unroll
        for (int j = 0; j < TN; ++j) {
            int n = n0 + wn + j * 16 + (lane & 15);
            if (n >= N) continue;
            float bn_ = bias_n ? bias_n[n] : 0.f;
            #pragma unroll
            for (int r = 0; r < 4; ++r) {
                int m = mbase + r;
                if (m >= M) continue;
                float t = acc[i][j][r] * alpha;
                if (scale_m) t *= scale_m[m];
                if (bias_m)  t += bias_m[m];
                t += bn_;
                long long idx = (long long)z * c_bs + (long long)m * ldc + n;
                if (resid) t += resid[idx];
                if (relu) t = fmaxf(t, 0.f);
                if (C)  C[idx] = t;
                if (Ch) {
                    u16 h = f2bf(t);
                    Ch[idx] = h;
                    Cl[idx] = f2bf(t - bf2f(h));
                }
            }
        }
    }
}

// ---------------------------------------------------------------------------
// Implicit-GEMM 3x3 conv, split-bf16, channels-last with zero-padded border.
// 2-phase double-buffered pipeline; wave-tile WTM x WTN (TM=8/TN=4 instance
// maximizes FLOP per LDS byte — the measured wall). A-fragments are loaded
// short-lived inside the i-loop to bound VGPR pressure.
// ---------------------------------------------------------------------------
template<int BM, int BN, int GWM, int GWN>
__global__ __launch_bounds__(256) void conv_gemm(
    const u16* __restrict__ Ih, const u16* __restrict__ Il,
    const u16* __restrict__ Wh, const u16* __restrict__ Wl,
    int Wd, int pW, int M, int N, int kper,
    float* __restrict__ Cp,
    float* __restrict__ C, u16* __restrict__ Ph, u16* __restrict__ Pl,
    const float* __restrict__ resid, const float* __restrict__ bias_n,
    const float* __restrict__ scale_n, int relu)
{
    constexpr int WTM = BM / GWM, WTN = BN / GWN;
    constexpr int TM = WTM / 16, TN = WTN / 16;
    constexpr int NLD = (BM / 64) * 2 + (BN / 64) * 2;
    __shared__ u16 Ash[2][BM * 32];
    __shared__ u16 Asl[2][BM * 32];
    __shared__ u16 Bsh[2][BN * 32];
    __shared__ u16 Bsl[2][BN * 32];
    const int tid = threadIdx.x;
    const int lane = tid & 63;
    const int w = tid >> 6;
    const int wm = (w % GWM) * WTM, wn = (w / GWM) * WTN;
    const int m0 = blockIdx.y * BM, n0 = blockIdx.x * BN;
    const int quad = lane >> 4;

    // per-slot pixel bases (padded HWC), chunk swizzle baked in
    long aoff[BM / 64];
    #pragma unroll
    for (int p = 0; p < BM / 64; ++p) {
        int idx = p * 256 + tid;
        int row = idx >> 2;
        int olog = (idx & 3) ^ ((row >> 1) & 3);
        int gr = m0 + row; if (gr > M - 1) gr = M - 1;
        int hh = gr / Wd, ww = gr - hh * Wd;
        aoff[p] = ((long)(hh + 1) * pW + (ww + 1)) * 512 + olog * 8;
    }
    long boff[BN / 64];
    #pragma unroll
    for (int p = 0; p < BN / 64; ++p) {
        int idx = p * 256 + tid;
        int row = idx >> 2;
        int olog = (idx & 3) ^ ((row >> 1) & 3);
        int gn = n0 + row; if (gn > N - 1) gn = N - 1;
        boff[p] = (long)gn * 4608 + olog * 8;
    }

    floatx4 acc[TM][TN];
    #pragma unroll
    for (int i = 0; i < TM; ++i)
        #pragma unroll
        for (int j = 0; j < TN; ++j)
            #pragma unroll
            for (int r = 0; r < 4; ++r) acc[i][j][r] = 0.f;

    auto stage = [&](int kt, int buf) {
        int r = kt >> 9;                       // tap index 0..8 (uniform)
        int rd = r / 3;
        long roff = ((long)(rd - 1) * pW + (r - 3 * rd - 1)) * 512 + (kt & 511);
        #pragma unroll
        for (int p = 0; p < BM / 64; ++p) {
            long go = aoff[p] + roff;
            gll16(Ih + go, &Ash[buf][(p * 256 + tid) * 8]);
            gll16(Il + go, &Asl[buf][(p * 256 + tid) * 8]);
        }
        #pragma unroll
        for (int p = 0; p < BN / 64; ++p) {
            long go = boff[p] + kt;
            gll16(Wh + go, &Bsh[buf][(p * 256 + tid) * 8]);
            gll16(Wl + go, &Bsl[buf][(p * 256 + tid) * 8]);
        }
    };

    const int k0 = blockIdx.z * kper, k1 = k0 + kper;
    stage(k0, 0);
    int cur = 0;
    for (int kt = k0; kt < k1; kt += 32) {
        if (kt + 32 < k1) {
            stage(kt + 32, cur ^ 1);
            asm volatile("s_waitcnt vmcnt(%0)" :: "n"(NLD) : "memory");
        } else {
            asm volatile("s_waitcnt vmcnt(0)" ::: "memory");
        }
        __builtin_amdgcn_s_barrier();
        asm volatile("" ::: "memory");

        bf16x8 bfh[TN], bfl[TN];
        #pragma unroll
        for (int j = 0; j < TN; ++j) {
            int row = wn + j * 16 + (lane & 15);
            int oph = quad ^ ((row >> 1) & 3);
            bfh[j] = *(const bf16x8*)&Bsh[cur][row * 32 + oph * 8];
            bfl[j] = *(const bf16x8*)&Bsl[cur][row * 32 + oph * 8];
        }
        #pragma unroll
        for (int i = 0; i < TM; ++i) {
            int row = wm + i * 16 + (lane & 15);
            int oph = quad ^ ((row >> 1) & 3);
            bf16x8 ah = *(const bf16x8*)&Ash[cur][row * 32 + oph * 8];
            bf16x8 al = *(const bf16x8*)&Asl[cur][row * 32 + oph * 8];
            #pragma unroll
            for (int j = 0; j < TN; ++j) {
                acc[i][j] = __builtin_amdgcn_mfma_f32_16x16x32_bf16(ah, bfl[j], acc[i][j], 0, 0, 0);
                acc[i][j] = __builtin_amdgcn_mfma_f32_16x16x32_bf16(al, bfh[j], acc[i][j], 0, 0, 0);
                acc[i][j] = __builtin_amdgcn_mfma_f32_16x16x32_bf16(ah, bfh[j], acc[i][j], 0, 0, 0);
            }
        }

        asm volatile("s_waitcnt lgkmcnt(0)" ::: "memory");
        __builtin_amdgcn_s_barrier();
        cur ^= 1;
    }

    const long zoff = (long)blockIdx.z * M * N;
    #pragma unroll
    for (int i = 0; i < TM; ++i) {
        int mbase = m0 + wm + i * 16 + quad * 4;
        #pragma unroll
        for (int j = 0; j < TN; ++j) {
            int n = n0 + wn + j * 16 + (lane & 15);
            if (n >= N) continue;
            float bn_ = bias_n ? bias_n[n] : 0.f;
            float sn_ = scale_n ? scale_n[n] : 1.f;
            #pragma unroll
            for (int rr = 0; rr < 4; ++rr) {
                int m = mbase + rr;
                if (m >= M) continue;
                long li = (long)m * N + n;
                if (Cp) { Cp[zoff + li] = acc[i][j][rr]; continue; }
                float t = acc[i][j][rr] * sn_ + bn_;
                if (resid) t += resid[li];
                if (relu) t = fmaxf(t, 0.f);
                if (C) C[li] = t;
                if (Ph) {
                    int hh = m / Wd, ww = m - hh * Wd;
                    long po = ((long)(hh + 1) * pW + ww + 1) * N + n;
                    u16 h2 = f2bf(t);
                    Ph[po] = h2;
                    Pl[po] = f2bf(t - bf2f(h2));
                }
            }
        }
    }
}

// split-K reduce + fused epilogue (N mult of 4)
__global__ __launch_bounds__(256) void reduce_ep(
    const float* __restrict__ Cp, int KS, int M, int N, int Wd, int pW,
    float* __restrict__ C, u16* __restrict__ Ph, u16* __restrict__ Pl,
    const float* __restrict__ resid, const float* __restrict__ bias_n,
    const float* __restrict__ scale_n, int relu)
{
    long i4 = (long)blockIdx.x * 256 + threadIdx.x;
    long MN = (long)M * N;
    if (i4 * 4 >= MN) return;
    long n4t = MN >> 2;
    float4 s = ((const float4*)Cp)[i4];
    for (int z = 1; z < KS; ++z) {
        float4 v = ((const float4*)Cp)[(long)z * n4t + i4];
        s.x += v.x; s.y += v.y; s.z += v.z; s.w += v.w;
    }
    long bse = i4 * 4;
    int n0 = (int)(bse % N);
    int m = (int)(bse / N);
    float t[4] = {s.x, s.y, s.z, s.w};
    #pragma unroll
    for (int e = 0; e < 4; ++e) {
        int n = n0 + e;
        if (scale_n) t[e] *= scale_n[n];
        if (bias_n)  t[e] += bias_n[n];
        if (resid)   t[e] += resid[bse + e];
        if (relu)    t[e] = fmaxf(t[e], 0.f);
    }
    if (C) {
        float4 o; o.x = t[0]; o.y = t[1]; o.z = t[2]; o.w = t[3];
        ((float4*)C)[i4] = o;
    }
    if (Ph) {
        int hh = m / Wd, ww = m - hh * Wd;
        long po = ((long)(hh + 1) * pW + ww + 1) * N + n0;
        ushort4 vh, vl;
        vh.x = f2bf(t[0]); vl.x = f2bf(t[0] - bf2f(vh.x));
        vh.y = f2bf(t[1]); vl.y = f2bf(t[1] - bf2f(vh.y));
        vh.z = f2bf(t[2]); vl.z = f2bf(t[2] - bf2f(vh.z));
        vh.w = f2bf(t[3]); vl.w = f2bf(t[3] - bf2f(vh.w));
        *(ushort4*)(Ph + po) = vh;
        *(ushort4*)(Pl + po) = vl;
    }
}

// weight reorder: OIHW w[co][ci][r] -> [co][r*512+ci], bf16 hi/lo
__global__ __launch_bounds__(256) void wreorder(const float* __restrict__ w,
                                                u16* __restrict__ Wh,
                                                u16* __restrict__ Wl, int total)
{
    int i = blockIdx.x * 256 + threadIdx.x;
    if (i >= total) return;
    int co = i / 4608;
    int k = i - co * 4608;
    int r = k >> 9, ci = k & 511;
    float v = w[co * 4608 + ci * 9 + r];
    u16 h = f2bf(v);
    Wh[i] = h;
    Wl[i] = f2bf(v - bf2f(h));
}

__global__ __launch_bounds__(256) void zero_f4(float4* p, int n4)
{
    int i = blockIdx.x * 256 + threadIdx.x;
    if (i < n4) { float4 z; z.x = z.y = z.z = z.w = 0.f; p[i] = z; }
}

// [Z][R][Cc] f32 -> [Z][Cc][R] bf16 hi/lo transpose (attention weights)
__global__ __launch_bounds__(256) void xpose_cast2(const float* __restrict__ src,
                                                   u16* __restrict__ dh,
                                                   u16* __restrict__ dl,
                                                   int R, int Cc)
{
    __shared__ float tile[32][33];
    const int z = blockIdx.z;
    const float* s = src + (long long)z * R * Cc;
    const long long zb = (long long)z * R * Cc;
    const int c0 = blockIdx.x * 32, r0 = blockIdx.y * 32;
    const int tc = threadIdx.x & 31, tr = threadIdx.x >> 5;
    #pragma unroll
    for (int q = 0; q < 4; ++q)
        tile[tr + q * 8][tc] = s[(long long)(r0 + tr + q * 8) * Cc + c0 + tc];
    __syncthreads();
    #pragma unroll
    for (int q = 0; q < 4; ++q) {
        float v = tile[tc][tr + q * 8];
        long long o = zb + (long long)(c0 + tr + q * 8) * R + r0 + tc;
        u16 h = f2bf(v);
        dh[o] = h;
        dl[o] = f2bf(v - bf2f(h));
    }
}

// x [512][1024] f32 -> X32 [1024][512] f32 + Xb hi/lo [1024][512] bf16
__global__ __launch_bounds__(256) void xpose_x2(const float* __restrict__ x,
                                                float* __restrict__ X32,
                                                u16* __restrict__ Xh,
                                                u16* __restrict__ Xl)
{
    __shared__ float tile[32][33];
    const int t0 = blockIdx.x * 32;
    const int c0 = blockIdx.y * 32;
    const int tc = threadIdx.x & 31, tr = threadIdx.x >> 5;
    #pragma unroll
    for (int q = 0; q < 4; ++q)
        tile[tr + q * 8][tc] = x[(long long)(c0 + tr + q * 8) * 1024 + t0 + tc];
    __syncthreads();
    #pragma unroll
    for (int q = 0; q < 4; ++q) {
        int tok = t0 + tr + q * 8, c = c0 + tc;
        float v = tile[tc][tr + q * 8];
        long long o = (long long)tok * 512 + c;
        X32[o] = v;
        u16 h = f2bf(v);
        Xh[o] = h;
        Xl[o] = f2bf(v - bf2f(h));
    }
}

// V^T hi/lo: QKV [1024][1536] cols 1024..1535 -> VT [512][1024]
__global__ __launch_bounds__(256) void vt_xpose2(const u16* __restrict__ Qh,
                                                 const u16* __restrict__ Ql,
                                                 u16* __restrict__ VTh,
                                                 u16* __restrict__ VTl)
{
    __shared__ u16 th[32][34];
    __shared__ u16 tl[32][34];
    const int c0 = blockIdx.x * 32;
    const int r0 = blockIdx.y * 32;
    const int tc = threadIdx.x & 31, tr = threadIdx.x >> 5;
    #pragma unroll
    for (int q = 0; q < 4; ++q) {
        long long o = (long long)(r0 + tr + q * 8) * 1536 + 1024 + c0 + tc;
        th[tr + q * 8][tc] = Qh[o];
        tl[tr + q * 8][tc] = Ql[o];
    }
    __syncthreads();
    #pragma unroll
    for (int q = 0; q < 4; ++q) {
        long long o = (long long)(c0 + tr + q * 8) * 1024 + r0 + tc;
        VTh[o] = th[tc][tr + q * 8];
        VTl[o] = tl[tc][tr + q * 8];
    }
}

// softmax over 1024 rows, f32 in -> bf16 hi/lo out
__global__ __launch_bounds__(256) void softmax_bf2(const float* __restrict__ S,
                                                   u16* __restrict__ Ph,
                                                   u16* __restrict__ Pl)
{
    __shared__ float rmax[4], rsum[4];
    const long long base = (long long)blockIdx.x * 1024;
    const int t = threadIdx.x;
    float4 v = *(const float4*)(S + base + t * 4);
    float mx = fmaxf(fmaxf(v.x, v.y), fmaxf(v.z, v.w));
    #pragma unroll
    for (int o = 32; o > 0; o >>= 1) mx = fmaxf(mx, __shfl_down(mx, o));
    if ((t & 63) == 0) rmax[t >> 6] = mx;
    __syncthreads();
    float m4 = fmaxf(fmaxf(rmax[0], rmax[1]), fmaxf(rmax[2], rmax[3]));
    v.x = expf(v.x - m4); v.y = expf(v.y - m4);
    v.z = expf(v.z - m4); v.w = expf(v.w - m4);
    float sm = v.x + v.y + v.z + v.w;
    #pragma unroll
    for (int o = 32; o > 0; o >>= 1) sm += __shfl_down(sm, o);
    if ((t & 63) == 0) rsum[t >> 6] = sm;
    __syncthreads();
    float inv = 1.f / (rsum[0] + rsum[1] + rsum[2] + rsum[3]);
    float p0 = v.x * inv, p1 = v.y * inv, p2 = v.z * inv, p3 = v.w * inv;
    ushort4 oh, ol;
    oh.x = f2bf(p0); ol.x = f2bf(p0 - bf2f(oh.x));
    oh.y = f2bf(p1); ol.y = f2bf(p1 - bf2f(oh.y));
    oh.z = f2bf(p2); ol.z = f2bf(p2 - bf2f(oh.z));
    oh.w = f2bf(p3); ol.w = f2bf(p3 - bf2f(oh.w));
    *(ushort4*)(Ph + base + t * 4) = oh;
    *(ushort4*)(Pl + base + t * 4) = ol;
}

// nearest grid_sample from token-major X [1024][512] -> padded HWC bf16 hi/lo
__global__ __launch_bounds__(256) void grid_sample_p(const float* __restrict__ X,
                                                     u16* __restrict__ Ph,
                                                     u16* __restrict__ Pl)
{
    int idx = blockIdx.x * 256 + threadIdx.x;
    if (idx >= 2500 * 512) return;
    int c = idx & 511;
    int p = idx >> 9;
    int i = p / 50, j = p - i * 50;
    float vy = -49.f + 2.f * i;
    float gy = (vy + 51.2f) / 102.4f * 2.f - 1.f;
    float fy = ((gy + 1.f) * 32.f - 1.f) * 0.5f;
    int iy = (int)roundf(fy);
    bool oky = (iy >= 0) && (iy < 32);
    iy = min(max(iy, 0), 31);
    float vx = -49.f + 2.f * j;
    float gx = (vx + 51.2f) / 102.4f * 2.f - 1.f;
    float fx = ((gx + 1.f) * 32.f - 1.f) * 0.5f;
    int ix = (int)roundf(fx);
    bool okx = (ix >= 0) && (ix < 32);
    ix = min(max(ix, 0), 31);
    int tok = iy * 32 + ix;
    float v = (oky && okx) ? X[(long)tok * 512 + c] : 0.f;
    long po = ((long)(i + 1) * 52 + (j + 1)) * 512 + c;
    u16 h = f2bf(v);
    Ph[po] = h;
    Pl[po] = f2bf(v - bf2f(h));
}

// pixel shuffle r=2: UPF HWC [2500][2048] -> padded HWC bf16 hi/lo (102x102x512)
__global__ __launch_bounds__(256) void pixshuf_p(const float* __restrict__ up,
                                                 u16* __restrict__ Ph,
                                                 u16* __restrict__ Pl)
{
    int idx = blockIdx.x * 256 + threadIdx.x;
    if (idx >= 10000 * 512) return;
    int c = idx & 511;
    int p = idx >> 9;
    int oh = p / 100, ow = p - oh * 100;
    int h = oh >> 1, r1 = oh & 1, w2 = ow >> 1, r2 = ow & 1;
    float v = up[(long)(h * 50 + w2) * 2048 + (c << 2) + (r1 << 1) + r2];
    long po = ((long)(oh + 1) * 102 + (ow + 1)) * 512 + c;
    u16 hh = f2bf(v);
    Ph[po] = hh;
    Pl[po] = f2bf(v - bf2f(hh));
}

__global__ __launch_bounds__(256) void bnprep(
    const float* g1, const float* b1, const float* m1, const float* v1,
    const float* g2, const float* b2, const float* m2, const float* v2,
    float* sc1, float* bi1, float* sc2, float* bi2)
{
    int c = blockIdx.x * 256 + threadIdx.x;
    if (c >= 512) return;
    float s1 = g1[c] * rsqrtf(v1[c] + 1e-5f);
    sc1[c] = s1; bi1[c] = b1[c] - m1[c] * s1;
    float s2 = g2[c] * rsqrtf(v2[c] + 1e-5f);
    sc2[c] = s2; bi2[c] = b2[c] - m2[c] * s2;
}

// 1x1 conv (512->6) + sigmoid from HWC f32; one wave per pixel
__global__ __launch_bounds__(256) void conv1x1_sig_h(const float* __restrict__ in,
                                                     const float* __restrict__ w,
                                                     const float* __restrict__ b,
                                                     float* __restrict__ out)
{
    int pix = blockIdx.x * 4 + (threadIdx.x >> 6);
    int lane = threadIdx.x & 63;
    const float* row = in + (long)pix * 512;
    float4 a0 = *(const float4*)(row + lane * 8);
    float4 a1 = *(const float4*)(row + lane * 8 + 4);
    float s[6];
    #pragma unroll
    for (int co = 0; co < 6; ++co) {
        const float* wr = w + co * 512 + lane * 8;
        float4 w0 = *(const float4*)wr;
        float4 w1 = *(const float4*)(wr + 4);
        s[co] = a0.x * w0.x + a0.y * w0.y + a0.z * w0.z + a0.w * w0.w
              + a1.x * w1.x + a1.y * w1.y + a1.z * w1.z + a1.w * w1.w;
    }
    #pragma unroll
    for (int co = 0; co < 6; ++co)
        #pragma unroll
        for (int o = 32; o > 0; o >>= 1) s[co] += __shfl_xor(s[co], o);
    if (lane < 6) {
        float t = s[lane] + b[lane];
        out[lane * 10000 + pix] = 1.f / (1.f + expf(-t));
    }
}

// ---------------------------------------------------------------------------
extern "C" void kernel_launch(void* const* d_in, const int* in_sizes, int n_in,
                              void* d_out, int out_size, void* d_ws, size_t ws_size,
                              hipStream_t stream)
{
    const float* x      = (const float*)d_in[0];
    const float* qkv_w  = (const float*)d_in[1];
    const float* proj_w = (const float*)d_in[2];
    const float* proj_b = (const float*)d_in[3];
    const float* head_w = (const float*)d_in[4];
    const float* head_b = (const float*)d_in[5];
    const float* body_w = (const float*)d_in[6];
    const float* body_b = (const float*)d_in[7];
    const float* btail_w= (const float*)d_in[8];
    const float* btail_b= (const float*)d_in[9];
    const float* up_w   = (const float*)d_in[10];
    const float* up_b   = (const float*)d_in[11];
    const float* tail_w = (const float*)d_in[12];
    const float* tail_b = (const float*)d_in[13];
    const float* c1_w   = (const float*)d_in[14];
    const float* bn1_g  = (const float*)d_in[15];
    const float* bn1_b  = (const float*)d_in[16];
    const float* bn1_m  = (const float*)d_in[17];
    const float* bn1_v  = (const float*)d_in[18];
    const float* c2_w   = (const float*)d_in[19];
    const float* bn2_g  = (const float*)d_in[20];
    const float* bn2_b  = (const float*)d_in[21];
    const float* bn2_m  = (const float*)d_in[22];
    const float* bn2_v  = (const float*)d_in[23];
    const float* c3_w   = (const float*)d_in[24];
    const float* c3_b   = (const float*)d_in[25];

    char* base = (char*)d_ws;
    // ---- Phase A (attention) arena — unchanged offsets ----
    float*          S    = (float*)(base + 0);                 // 8x1024x1024 f32
    u16*            P_h  = (u16*)(base + 33554432);
    u16*            P_l  = (u16*)(base + 50331648);
    u16*            Q_h  = (u16*)(base + 67108864);            // 1024x1536
    u16*            Q_l  = (u16*)(base + 70254592);
    u16*            VT_h = (u16*)(base + 73400320);            // 512x1024
    u16*            VT_l = (u16*)(base + 74448896);
    u16*            qw_h = (u16*)(base + 75497472);            // 8x1536x512
    u16*            qw_l = (u16*)(base + 88080384);
    u16*            pw_h = (u16*)(base + 100663296);           // 8x512x512
    u16*            pw_l = (u16*)(base + 104857600);
    u16*            O_h  = (u16*)(base + 109051904);           // 1024x512
    u16*            O_l  = (u16*)(base + 110100480);
    float*          X32b = (float*)(base + 111149056);         // 1024x512 f32
    u16*            X_h  = (u16*)(base + 113246208);
    u16*            X_l  = (u16*)(base + 114294784);
    float*          X32a = (float*)(base + 115343360);         // survives to grid_sample
    // ---- Phase B (conv) arena — reuses Phase A scratch (all writes post-attn) ----
    u16*   WB_h = (u16*)(base + 0);                  // reordered weights, <=2048x4608
    u16*   WB_l = (u16*)(base + 18874368);
    u16*   PX_h = (u16*)(base + 37748736);           // padded 52x52x512 bf16 each
    u16*   PX_l = (u16*)(base + 40517632);
    u16*   PA_h = (u16*)(base + 43286528);
    u16*   PA_l = (u16*)(base + 46055424);
    u16*   PB_h = (u16*)(base + 48824320);
    u16*   PB_l = (u16*)(base + 51593216);           // 50x50 pads end @54362112
    float* HhF  = (float*)(base + 54362112);         // 2500x512 f32 HWC
    float* RF1  = (float*)(base + 59482112);
    float* RF2  = (float*)(base + 64602112);
    float* Cp6  = (float*)(base + 69722112);         // split-K partials 6x2500x512 (50x50)
                                                     // 30.7MB: spans old-Cp + UPF region
                                                     // (UPF dead until up-conv; disjoint from
                                                     //  HhF/RF1/RF2 and 50x50 pads)
    float* Cp2  = (float*)(base + 37748736);         // split-K partials 2x10000x512 (100x100)
                                                     // 41MB, ends @78.7MB (PX..Cp6 dead then)
    float* UPF  = (float*)(base + 85082112);         // 2500x2048 f32 HWC
    float* Z2F  = (float*)(base + 85082112);         // alias (UPF dead after pixshuf)
    u16*   PU_h = (u16*)(base + 105562112);          // padded 102x102x512 bf16 each
    u16*   PU_l = (u16*)(base + 116215808);
    u16*   PY_h = (u16*)(base + 126869504);
    u16*   PY_l = (u16*)(base + 137523200);          // 100x100 pads end @148176896
    float* SC1  = (float*)(base + 151494656);
    float* BI1  = SC1 + 512;
    float* SC2  = BI1 + 512;
    float* BI2  = SC2 + 512;

    const float scale = 0.044194173824159216f;  // 512^-0.5

    // ---- prep ----
    xpose_cast2<<<dim3(48, 16, 8), 256, 0, stream>>>(qkv_w, qw_h, qw_l, 512, 1536);
    xpose_cast2<<<dim3(16, 16, 8), 256, 0, stream>>>(proj_w, pw_h, pw_l, 512, 512);
    xpose_x2<<<dim3(32, 16), 256, 0, stream>>>(x, X32a, X_h, X_l);

    // ---- 8 self-attention blocks ----
    for (int i = 0; i < 8; ++i) {
        float* Xold = (i % 2 == 0) ? X32a : X32b;
        float* Xnew = (i % 2 == 0) ? X32b : X32a;
        // qkv: [1024][1536] hi/lo   (64x64 tiles: 384 blocks)
        gemm3_nt<64, 64, 1, 4><<<dim3(24, 16, 1), 256, 0, stream>>>(
            X_h, X_l, 512, 0, qw_h + (long long)i * 786432, qw_l + (long long)i * 786432, 512, 0,
            nullptr, Q_h, Q_l, 1536, 0, nullptr, 1024, 1536, 512, 1.f,
            nullptr, nullptr, nullptr, 0);
        // scores per head -> S f32   (512 blocks, 2-resident)
        gemm3_nt<128, 128, 2, 2><<<dim3(8, 8, 8), 256, 0, stream>>>(
            Q_h, Q_l, 1536, 64, Q_h + 512, Q_l + 512, 1536, 64,
            S, nullptr, nullptr, 1024, 1048576, nullptr, 1024, 1024, 64, scale,
            nullptr, nullptr, nullptr, 0);
        softmax_bf2<<<8192, 256, 0, stream>>>(S, P_h, P_l);
        vt_xpose2<<<dim3(16, 32), 256, 0, stream>>>(Q_h, Q_l, VT_h, VT_l);
        // PV -> O hi/lo [1024][512]
        gemm3_nt<64, 64, 1, 4><<<dim3(1, 16, 8), 256, 0, stream>>>(
            P_h, P_l, 1024, 1048576, VT_h, VT_l, 1024, 65536,
            nullptr, O_h, O_l, 512, 64, nullptr, 1024, 64, 1024, 1.f,
            nullptr, nullptr, nullptr, 0);
        // proj + residual -> Xnew f32 + X hi/lo bf16
        gemm3_nt<64, 64, 1, 4><<<dim3(8, 16, 1), 256, 0, stream>>>(
            O_h, O_l, 512, 0, pw_h + (long long)i * 262144, pw_l + (long long)i * 262144, 512, 0,
            Xnew, X_h, X_l, 512, 0, Xold, 1024, 512, 512, 1.f,
            nullptr, nullptr, proj_b + i * 512, 0);
    }
    // final X in X32a (layer 7 writes X32a)

    // ---- zero padded 50x50 buffers (one contiguous span), then grid sample ----
    zero_f4<<<DIV_UP(1038336, 256), 256, 0, stream>>>((float4*)(base + 37748736), 1038336);
    grid_sample_p<<<DIV_UP(1280000, 256), 256, 0, stream>>>(X32a, PX_h, PX_l);
    // X32a now dead -> zero the padded 100x100 span (overlaps X32a)
    zero_f4<<<DIV_UP(2663424, 256), 256, 0, stream>>>((float4*)(base + 105562112), 2663424);

    // ---- implicit-GEMM conv3x3 — all via <128,256,1,4>: wave-tile 128x64 ----
    auto convK = [&](const u16* iPh, const u16* iPl, int H, int Wd,
                     const float* wsrc, int Cout, const float* bias, const float* scl,
                     const float* resid, int relu,
                     float* outC, u16* oPh, u16* oPl) {
        int pW = Wd + 2, M = H * Wd;
        int tot = Cout * 4608;
        wreorder<<<DIV_UP(tot, 256), 256, 0, stream>>>(wsrc, WB_h, WB_l, tot);
        if (Cout == 512 && M == 2500) {
            // 50x50: split-K z=6 (kper=768): 2x20x6 = 240 blocks (~1/CU)
            conv_gemm<128, 256, 1, 4><<<dim3(2, DIV_UP(M, 128), 6), 256, 0, stream>>>(
                iPh, iPl, WB_h, WB_l, Wd, pW, M, 512, 768, Cp6,
                nullptr, nullptr, nullptr, nullptr, nullptr, nullptr, 0);
            reduce_ep<<<DIV_UP(M * 512 / 4, 256), 256, 0, stream>>>(
                Cp6, 6, M, 512, Wd, pW, outC, oPh, oPl, resid, bias, scl, relu);
        } else if (Cout == 512) {
            // 100x100: split-K z=2 (kper=2304): 2x79x2 = 316 blocks
            conv_gemm<128, 256, 1, 4><<<dim3(2, DIV_UP(M, 128), 2), 256, 0, stream>>>(
                iPh, iPl, WB_h, WB_l, Wd, pW, M, 512, 2304, Cp2,
                nullptr, nullptr, nullptr, nullptr, nullptr, nullptr, 0);
            reduce_ep<<<DIV_UP(M * 512 / 4, 256), 256, 0, stream>>>(
                Cp2, 2, M, 512, Wd, pW, outC, oPh, oPl, resid, bias, scl, relu);
        } else {
            // up-conv 2048-out @50x50: 8x20 = 160 blocks, fused epilogue
            conv_gemm<128, 256, 1, 4><<<dim3(8, DIV_UP(M, 128), 1), 256, 0, stream>>>(
                iPh, iPl, WB_h, WB_l, Wd, pW, M, 2048, 4608, nullptr,
                outC, oPh, oPl, resid, bias, scl, relu);
        }
    };

    // EDSR head
    convK(PX_h, PX_l, 50, 50, head_w, 512, head_b, nullptr, nullptr, 0, HhF, PA_h, PA_l);
    // body resblocks
    const float* rres = HhF;
    float* RFs[2] = {RF1, RF2};
    for (int i = 0; i < 8; ++i) {
        convK(PA_h, PA_l, 50, 50, body_w + (long long)(2 * i) * 2359296, 512,
              body_b + 2 * i * 512, nullptr, nullptr, 1, nullptr, PB_h, PB_l);
        float* Rout = RFs[i & 1];
        convK(PB_h, PB_l, 50, 50, body_w + (long long)(2 * i + 1) * 2359296, 512,
              body_b + (2 * i + 1) * 512, nullptr, rres, 0, Rout, PA_h, PA_l);
        rres = Rout;
    }
    // body tail + skip
    convK(PA_h, PA_l, 50, 50, btail_w, 512, btail_b, nullptr, HhF, 0, nullptr, PB_h, PB_l);
    // upsample conv (512 -> 2048) to HWC f32  (Cp6 dead; UPF region now in use)
    convK(PB_h, PB_l, 50, 50, up_w, 2048, up_b, nullptr, nullptr, 0, UPF, nullptr, nullptr);
    pixshuf_p<<<DIV_UP(5120000, 256), 256, 0, stream>>>(UPF, PU_h, PU_l);
    // tail conv @100x100  (PX/PA/PB + HhF/RF now dead -> Cp2 region free)
    convK(PU_h, PU_l, 100, 100, tail_w, 512, tail_b, nullptr, nullptr, 0, nullptr, PY_h, PY_l);

    // classifier
    bnprep<<<2, 256, 0, stream>>>(bn1_g, bn1_b, bn1_m, bn1_v,
                                  bn2_g, bn2_b, bn2_m, bn2_v, SC1, BI1, SC2, BI2);
    convK(PY_h, PY_l, 100, 100, c1_w, 512, BI1, SC1, nullptr, 1, nullptr, PU_h, PU_l);
    convK(PU_h, PU_l, 100, 100, c2_w, 512, BI2, SC2, nullptr, 1, Z2F, nullptr, nullptr);
    conv1x1_sig_h<<<2500, 256, 0, stream>>>(Z2F, c3_w, c3_b, (float*)d_out);
}

// Round 7
// 3150.566 us; speedup vs baseline: 1.1936x; 1.1936x over previous
//
#include <hip/hip_runtime.h>
#include <math.h>

#define DIV_UP(a,b) (((a)+(b)-1)/(b))

typedef __bf16 bf16x8 __attribute__((ext_vector_type(8)));
typedef float floatx4 __attribute__((ext_vector_type(4)));
typedef unsigned short u16;

__device__ __forceinline__ u16 f2bf(float f) {
    unsigned u = __builtin_bit_cast(unsigned, f);
    u = (u + 0x7fffu + ((u >> 16) & 1u)) >> 16;
    return (u16)u;
}
__device__ __forceinline__ float bf2f(u16 h) {
    unsigned u = ((unsigned)h) << 16;
    return __builtin_bit_cast(float, u);
}

// async global->LDS, 16B per lane (dest = wave-uniform base + lane*16; global addr per-lane)
__device__ __forceinline__ void gll16(const void* g, void* l) {
    __builtin_amdgcn_global_load_lds(
        (const __attribute__((address_space(1))) void*)g,
        (__attribute__((address_space(3))) void*)l, 16, 0, 0);
}

// ---------------------------------------------------------------------------
// Split-bf16 NT GEMM (fp32-accurate): C = alpha*sum_k A[m][k]*B[n][k] + epi.
// 2-phase double-buffered pipeline with counted vmcnt. (attention phase)
// ---------------------------------------------------------------------------
template<int BM, int BN, int GWM, int GWN>
__global__ __launch_bounds__(256) void gemm3_nt(
    const u16* __restrict__ Ah, const u16* __restrict__ Al,
    int lda, long long a_bs,
    const u16* __restrict__ Bh, const u16* __restrict__ Bl,
    int ldb, long long b_bs,
    float* C, u16* Ch, u16* Cl, int ldc, long long c_bs,
    const float* resid, int M, int N, int K, float alpha,
    const float* __restrict__ bias_m, const float* __restrict__ scale_m,
    const float* __restrict__ bias_n, int relu)
{
    constexpr int WTM = BM / GWM, WTN = BN / GWN;
    constexpr int TM = WTM / 16, TN = WTN / 16;
    constexpr int NLD = (BM / 64) * 2 + (BN / 64) * 2;  // gll16 per thread per tile
    __shared__ u16 Ash[2][BM * 32];
    __shared__ u16 Asl[2][BM * 32];
    __shared__ u16 Bsh[2][BN * 32];
    __shared__ u16 Bsl[2][BN * 32];
    const int tid = threadIdx.x;
    const int lane = tid & 63;
    const int w = tid >> 6;
    const int wm = (w % GWM) * WTM, wn = (w / GWM) * WTN;
    const int m0 = blockIdx.y * BM, n0 = blockIdx.x * BN;
    const int z = blockIdx.z;
    const u16* Ahb = Ah + (long long)z * a_bs;
    const u16* Alb = Al + (long long)z * a_bs;
    const u16* Bhb = Bh + (long long)z * b_bs;
    const u16* Blb = Bl + (long long)z * b_bs;
    const int quad = lane >> 4;

    floatx4 acc[TM][TN];
    #pragma unroll
    for (int i = 0; i < TM; ++i)
        #pragma unroll
        for (int j = 0; j < TN; ++j)
            #pragma unroll
            for (int r = 0; r < 4; ++r) acc[i][j][r] = 0.f;

    auto stage = [&](int kt, int buf) {
        #pragma unroll
        for (int p = 0; p < BM / 64; ++p) {
            int idx = p * 256 + tid;
            int row = idx >> 2;
            int olog = (idx & 3) ^ ((row >> 1) & 3);
            int gr = m0 + row; if (gr > M - 1) gr = M - 1;
            long long go = (long long)gr * lda + kt + olog * 8;
            gll16(Ahb + go, &Ash[buf][idx * 8]);
            gll16(Alb + go, &Asl[buf][idx * 8]);
        }
        #pragma unroll
        for (int p = 0; p < BN / 64; ++p) {
            int idx = p * 256 + tid;
            int row = idx >> 2;
            int olog = (idx & 3) ^ ((row >> 1) & 3);
            int gr = n0 + row; if (gr > N - 1) gr = N - 1;
            long long go = (long long)gr * ldb + kt + olog * 8;
            gll16(Bhb + go, &Bsh[buf][idx * 8]);
            gll16(Blb + go, &Bsl[buf][idx * 8]);
        }
    };

    stage(0, 0);
    int cur = 0;
    for (int kt = 0; kt < K; kt += 32) {
        if (kt + 32 < K) {
            stage(kt + 32, cur ^ 1);
            asm volatile("s_waitcnt vmcnt(%0)" :: "n"(NLD) : "memory");
        } else {
            asm volatile("s_waitcnt vmcnt(0)" ::: "memory");
        }
        __builtin_amdgcn_s_barrier();
        asm volatile("" ::: "memory");

        bf16x8 afh[TM], afl[TM], bfh[TN], bfl[TN];
        #pragma unroll
        for (int i = 0; i < TM; ++i) {
            int row = wm + i * 16 + (lane & 15);
            int oph = quad ^ ((row >> 1) & 3);
            afh[i] = *(const bf16x8*)&Ash[cur][row * 32 + oph * 8];
            afl[i] = *(const bf16x8*)&Asl[cur][row * 32 + oph * 8];
        }
        #pragma unroll
        for (int j = 0; j < TN; ++j) {
            int row = wn + j * 16 + (lane & 15);
            int oph = quad ^ ((row >> 1) & 3);
            bfh[j] = *(const bf16x8*)&Bsh[cur][row * 32 + oph * 8];
            bfl[j] = *(const bf16x8*)&Bsl[cur][row * 32 + oph * 8];
        }
        #pragma unroll
        for (int i = 0; i < TM; ++i)
            #pragma unroll
            for (int j = 0; j < TN; ++j) {
                acc[i][j] = __builtin_amdgcn_mfma_f32_16x16x32_bf16(afh[i], bfl[j], acc[i][j], 0, 0, 0);
                acc[i][j] = __builtin_amdgcn_mfma_f32_16x16x32_bf16(afl[i], bfh[j], acc[i][j], 0, 0, 0);
                acc[i][j] = __builtin_amdgcn_mfma_f32_16x16x32_bf16(afh[i], bfh[j], acc[i][j], 0, 0, 0);
            }

        asm volatile("s_waitcnt lgkmcnt(0)" ::: "memory");
        __builtin_amdgcn_s_barrier();
        cur ^= 1;
    }

    #pragma unroll
    for (int i = 0; i < TM; ++i) {
        int mbase = m0 + wm + i * 16 + quad * 4;
        #pragma unroll
        for (int j = 0; j < TN; ++j) {
            int n = n0 + wn + j * 16 + (lane & 15);
            if (n >= N) continue;
            float bn_ = bias_n ? bias_n[n] : 0.f;
            #pragma unroll
            for (int r = 0; r < 4; ++r) {
                int m = mbase + r;
                if (m >= M) continue;
                float t = acc[i][j][r] * alpha;
                if (scale_m) t *= scale_m[m];
                if (bias_m)  t += bias_m[m];
                t += bn_;
                long long idx = (long long)z * c_bs + (long long)m * ldc + n;
                if (resid) t += resid[idx];
                if (relu) t = fmaxf(t, 0.f);
                if (C)  C[idx] = t;
                if (Ch) {
                    u16 h = f2bf(t);
                    Ch[idx] = h;
                    Cl[idx] = f2bf(t - bf2f(h));
                }
            }
        }
    }
}

// ---------------------------------------------------------------------------
// Implicit-GEMM 3x3 conv, split-bf16, channels-last with zero-padded border.
// 2-phase double-buffered pipeline + XCD-locality block swizzle: each XCD
// owns a contiguous y-range so the A-panel (im2col re-reads) stays in its
// private 4MB L2 (measured wall: FETCH 346MB @1.7TB/s = dispatch time).
// ---------------------------------------------------------------------------
template<int BM, int BN, int GWM, int GWN>
__global__ __launch_bounds__(256) void conv_gemm(
    const u16* __restrict__ Ih, const u16* __restrict__ Il,
    const u16* __restrict__ Wh, const u16* __restrict__ Wl,
    int Wd, int pW, int M, int N, int kper,
    float* __restrict__ Cp,
    float* __restrict__ C, u16* __restrict__ Ph, u16* __restrict__ Pl,
    const float* __restrict__ resid, const float* __restrict__ bias_n,
    const float* __restrict__ scale_n, int relu)
{
    constexpr int WTM = BM / GWM, WTN = BN / GWN;
    constexpr int TM = WTM / 16, TN = WTN / 16;
    constexpr int NLD = (BM / 64) * 2 + (BN / 64) * 2;
    __shared__ u16 Ash[2][BM * 32];
    __shared__ u16 Asl[2][BM * 32];
    __shared__ u16 Bsh[2][BN * 32];
    __shared__ u16 Bsl[2][BN * 32];
    const int tid = threadIdx.x;
    const int lane = tid & 63;
    const int w = tid >> 6;
    const int wm = (w % GWM) * WTM, wn = (w / GWM) * WTN;

    // XCD-locality swizzle: linear id -> (xcd-chunk of consecutive y)
    int bx = blockIdx.x, by = blockIdx.y, bz = blockIdx.z;
    {
        int gx = gridDim.x, gy = gridDim.y, gz = gridDim.z;
        int total = gx * gy * gz;
        if ((total & 7) == 0) {
            int l = (bz * gy + by) * gx + bx;
            int s = (l & 7) * (total >> 3) + (l >> 3);
            int xz = gx * gz;
            by = s / xz;
            int r = s - by * xz;
            bx = r % gx;
            bz = r / gx;
        }
    }
    const int m0 = by * BM, n0 = bx * BN;
    const int quad = lane >> 4;

    // per-slot pixel bases (padded HWC), chunk swizzle baked in
    long aoff[BM / 64];
    #pragma unroll
    for (int p = 0; p < BM / 64; ++p) {
        int idx = p * 256 + tid;
        int row = idx >> 2;
        int olog = (idx & 3) ^ ((row >> 1) & 3);
        int gr = m0 + row; if (gr > M - 1) gr = M - 1;
        int hh = gr / Wd, ww = gr - hh * Wd;
        aoff[p] = ((long)(hh + 1) * pW + (ww + 1)) * 512 + olog * 8;
    }
    long boff[BN / 64];
    #pragma unroll
    for (int p = 0; p < BN / 64; ++p) {
        int idx = p * 256 + tid;
        int row = idx >> 2;
        int olog = (idx & 3) ^ ((row >> 1) & 3);
        int gn = n0 + row; if (gn > N - 1) gn = N - 1;
        boff[p] = (long)gn * 4608 + olog * 8;
    }

    floatx4 acc[TM][TN];
    #pragma unroll
    for (int i = 0; i < TM; ++i)
        #pragma unroll
        for (int j = 0; j < TN; ++j)
            #pragma unroll
            for (int r = 0; r < 4; ++r) acc[i][j][r] = 0.f;

    auto stage = [&](int kt, int buf) {
        int r = kt >> 9;                       // tap index 0..8 (uniform)
        int rd = r / 3;
        long roff = ((long)(rd - 1) * pW + (r - 3 * rd - 1)) * 512 + (kt & 511);
        #pragma unroll
        for (int p = 0; p < BM / 64; ++p) {
            long go = aoff[p] + roff;
            gll16(Ih + go, &Ash[buf][(p * 256 + tid) * 8]);
            gll16(Il + go, &Asl[buf][(p * 256 + tid) * 8]);
        }
        #pragma unroll
        for (int p = 0; p < BN / 64; ++p) {
            long go = boff[p] + kt;
            gll16(Wh + go, &Bsh[buf][(p * 256 + tid) * 8]);
            gll16(Wl + go, &Bsl[buf][(p * 256 + tid) * 8]);
        }
    };

    const int k0 = bz * kper, k1 = k0 + kper;
    stage(k0, 0);
    int cur = 0;
    for (int kt = k0; kt < k1; kt += 32) {
        if (kt + 32 < k1) {
            stage(kt + 32, cur ^ 1);
            asm volatile("s_waitcnt vmcnt(%0)" :: "n"(NLD) : "memory");
        } else {
            asm volatile("s_waitcnt vmcnt(0)" ::: "memory");
        }
        __builtin_amdgcn_s_barrier();
        asm volatile("" ::: "memory");

        bf16x8 afh[TM], afl[TM], bfh[TN], bfl[TN];
        #pragma unroll
        for (int i = 0; i < TM; ++i) {
            int row = wm + i * 16 + (lane & 15);
            int oph = quad ^ ((row >> 1) & 3);
            afh[i] = *(const bf16x8*)&Ash[cur][row * 32 + oph * 8];
            afl[i] = *(const bf16x8*)&Asl[cur][row * 32 + oph * 8];
        }
        #pragma unroll
        for (int j = 0; j < TN; ++j) {
            int row = wn + j * 16 + (lane & 15);
            int oph = quad ^ ((row >> 1) & 3);
            bfh[j] = *(const bf16x8*)&Bsh[cur][row * 32 + oph * 8];
            bfl[j] = *(const bf16x8*)&Bsl[cur][row * 32 + oph * 8];
        }
        #pragma unroll
        for (int i = 0; i < TM; ++i)
            #pragma unroll
            for (int j = 0; j < TN; ++j) {
                acc[i][j] = __builtin_amdgcn_mfma_f32_16x16x32_bf16(afh[i], bfl[j], acc[i][j], 0, 0, 0);
                acc[i][j] = __builtin_amdgcn_mfma_f32_16x16x32_bf16(afl[i], bfh[j], acc[i][j], 0, 0, 0);
                acc[i][j] = __builtin_amdgcn_mfma_f32_16x16x32_bf16(afh[i], bfh[j], acc[i][j], 0, 0, 0);
            }

        asm volatile("s_waitcnt lgkmcnt(0)" ::: "memory");
        __builtin_amdgcn_s_barrier();
        cur ^= 1;
    }

    const long zoff = (long)bz * M * N;
    #pragma unroll
    for (int i = 0; i < TM; ++i) {
        int mbase = m0 + wm + i * 16 + quad * 4;
        #pragma unroll
        for (int j = 0; j < TN; ++j) {
            int n = n0 + wn + j * 16 + (lane & 15);
            if (n >= N) continue;
            float bn_ = bias_n ? bias_n[n] : 0.f;
            float sn_ = scale_n ? scale_n[n] : 1.f;
            #pragma unroll
            for (int rr = 0; rr < 4; ++rr) {
                int m = mbase + rr;
                if (m >= M) continue;
                long li = (long)m * N + n;
                if (Cp) { Cp[zoff + li] = acc[i][j][rr]; continue; }
                float t = acc[i][j][rr] * sn_ + bn_;
                if (resid) t += resid[li];
                if (relu) t = fmaxf(t, 0.f);
                if (C) C[li] = t;
                if (Ph) {
                    int hh = m / Wd, ww = m - hh * Wd;
                    long po = ((long)(hh + 1) * pW + ww + 1) * N + n;
                    u16 h2 = f2bf(t);
                    Ph[po] = h2;
                    Pl[po] = f2bf(t - bf2f(h2));
                }
            }
        }
    }
}

// split-K reduce + fused epilogue (N mult of 4)
__global__ __launch_bounds__(256) void reduce_ep(
    const float* __restrict__ Cp, int KS, int M, int N, int Wd, int pW,
    float* __restrict__ C, u16* __restrict__ Ph, u16* __restrict__ Pl,
    const float* __restrict__ resid, const float* __restrict__ bias_n,
    const float* __restrict__ scale_n, int relu)
{
    long i4 = (long)blockIdx.x * 256 + threadIdx.x;
    long MN = (long)M * N;
    if (i4 * 4 >= MN) return;
    long n4t = MN >> 2;
    float4 s = ((const float4*)Cp)[i4];
    for (int z = 1; z < KS; ++z) {
        float4 v = ((const float4*)Cp)[(long)z * n4t + i4];
        s.x += v.x; s.y += v.y; s.z += v.z; s.w += v.w;
    }
    long bse = i4 * 4;
    int n0 = (int)(bse % N);
    int m = (int)(bse / N);
    float t[4] = {s.x, s.y, s.z, s.w};
    #pragma unroll
    for (int e = 0; e < 4; ++e) {
        int n = n0 + e;
        if (scale_n) t[e] *= scale_n[n];
        if (bias_n)  t[e] += bias_n[n];
        if (resid)   t[e] += resid[bse + e];
        if (relu)    t[e] = fmaxf(t[e], 0.f);
    }
    if (C) {
        float4 o; o.x = t[0]; o.y = t[1]; o.z = t[2]; o.w = t[3];
        ((float4*)C)[i4] = o;
    }
    if (Ph) {
        int hh = m / Wd, ww = m - hh * Wd;
        long po = ((long)(hh + 1) * pW + ww + 1) * N + n0;
        ushort4 vh, vl;
        vh.x = f2bf(t[0]); vl.x = f2bf(t[0] - bf2f(vh.x));
        vh.y = f2bf(t[1]); vl.y = f2bf(t[1] - bf2f(vh.y));
        vh.z = f2bf(t[2]); vl.z = f2bf(t[2] - bf2f(vh.z));
        vh.w = f2bf(t[3]); vl.w = f2bf(t[3] - bf2f(vh.w));
        *(ushort4*)(Ph + po) = vh;
        *(ushort4*)(Pl + po) = vl;
    }
}

// weight reorder: OIHW w[co][ci][r] -> [co][r*512+ci], bf16 hi/lo
__global__ __launch_bounds__(256) void wreorder(const float* __restrict__ w,
                                                u16* __restrict__ Wh,
                                                u16* __restrict__ Wl, int total)
{
    int i = blockIdx.x * 256 + threadIdx.x;
    if (i >= total) return;
    int co = i / 4608;
    int k = i - co * 4608;
    int r = k >> 9, ci = k & 511;
    float v = w[co * 4608 + ci * 9 + r];
    u16 h = f2bf(v);
    Wh[i] = h;
    Wl[i] = f2bf(v - bf2f(h));
}

__global__ __launch_bounds__(256) void zero_f4(float4* p, int n4)
{
    int i = blockIdx.x * 256 + threadIdx.x;
    if (i < n4) { float4 z; z.x = z.y = z.z = z.w = 0.f; p[i] = z; }
}

// [Z][R][Cc] f32 -> [Z][Cc][R] bf16 hi/lo transpose (attention weights)
__global__ __launch_bounds__(256) void xpose_cast2(const float* __restrict__ src,
                                                   u16* __restrict__ dh,
                                                   u16* __restrict__ dl,
                                                   int R, int Cc)
{
    __shared__ float tile[32][33];
    const int z = blockIdx.z;
    const float* s = src + (long long)z * R * Cc;
    const long long zb = (long long)z * R * Cc;
    const int c0 = blockIdx.x * 32, r0 = blockIdx.y * 32;
    const int tc = threadIdx.x & 31, tr = threadIdx.x >> 5;
    #pragma unroll
    for (int q = 0; q < 4; ++q)
        tile[tr + q * 8][tc] = s[(long long)(r0 + tr + q * 8) * Cc + c0 + tc];
    __syncthreads();
    #pragma unroll
    for (int q = 0; q < 4; ++q) {
        float v = tile[tc][tr + q * 8];
        long long o = zb + (long long)(c0 + tr + q * 8) * R + r0 + tc;
        u16 h = f2bf(v);
        dh[o] = h;
        dl[o] = f2bf(v - bf2f(h));
    }
}

// x [512][1024] f32 -> X32 [1024][512] f32 + Xb hi/lo [1024][512] bf16
__global__ __launch_bounds__(256) void xpose_x2(const float* __restrict__ x,
                                                float* __restrict__ X32,
                                                u16* __restrict__ Xh,
                                                u16* __restrict__ Xl)
{
    __shared__ float tile[32][33];
    const int t0 = blockIdx.x * 32;
    const int c0 = blockIdx.y * 32;
    const int tc = threadIdx.x & 31, tr = threadIdx.x >> 5;
    #pragma unroll
    for (int q = 0; q < 4; ++q)
        tile[tr + q * 8][tc] = x[(long long)(c0 + tr + q * 8) * 1024 + t0 + tc];
    __syncthreads();
    #pragma unroll
    for (int q = 0; q < 4; ++q) {
        int tok = t0 + tr + q * 8, c = c0 + tc;
        float v = tile[tc][tr + q * 8];
        long long o = (long long)tok * 512 + c;
        X32[o] = v;
        u16 h = f2bf(v);
        Xh[o] = h;
        Xl[o] = f2bf(v - bf2f(h));
    }
}

// V^T hi/lo: QKV [1024][1536] cols 1024..1535 -> VT [512][1024]
__global__ __launch_bounds__(256) void vt_xpose2(const u16* __restrict__ Qh,
                                                 const u16* __restrict__ Ql,
                                                 u16* __restrict__ VTh,
                                                 u16* __restrict__ VTl)
{
    __shared__ u16 th[32][34];
    __shared__ u16 tl[32][34];
    const int c0 = blockIdx.x * 32;
    const int r0 = blockIdx.y * 32;
    const int tc = threadIdx.x & 31, tr = threadIdx.x >> 5;
    #pragma unroll
    for (int q = 0; q < 4; ++q) {
        long long o = (long long)(r0 + tr + q * 8) * 1536 + 1024 + c0 + tc;
        th[tr + q * 8][tc] = Qh[o];
        tl[tr + q * 8][tc] = Ql[o];
    }
    __syncthreads();
    #pragma unroll
    for (int q = 0; q < 4; ++q) {
        long long o = (long long)(c0 + tr + q * 8) * 1024 + r0 + tc;
        VTh[o] = th[tc][tr + q * 8];
        VTl[o] = tl[tc][tr + q * 8];
    }
}

// softmax over 1024 rows, f32 in -> bf16 hi/lo out
__global__ __launch_bounds__(256) void softmax_bf2(const float* __restrict__ S,
                                                   u16* __restrict__ Ph,
                                                   u16* __restrict__ Pl)
{
    __shared__ float rmax[4], rsum[4];
    const long long base = (long long)blockIdx.x * 1024;
    const int t = threadIdx.x;
    float4 v = *(const float4*)(S + base + t * 4);
    float mx = fmaxf(fmaxf(v.x, v.y), fmaxf(v.z, v.w));
    #pragma unroll
    for (int o = 32; o > 0; o >>= 1) mx = fmaxf(mx, __shfl_down(mx, o));
    if ((t & 63) == 0) rmax[t >> 6] = mx;
    __syncthreads();
    float m4 = fmaxf(fmaxf(rmax[0], rmax[1]), fmaxf(rmax[2], rmax[3]));
    v.x = expf(v.x - m4); v.y = expf(v.y - m4);
    v.z = expf(v.z - m4); v.w = expf(v.w - m4);
    float sm = v.x + v.y + v.z + v.w;
    #pragma unroll
    for (int o = 32; o > 0; o >>= 1) sm += __shfl_down(sm, o);
    if ((t & 63) == 0) rsum[t >> 6] = sm;
    __syncthreads();
    float inv = 1.f / (rsum[0] + rsum[1] + rsum[2] + rsum[3]);
    float p0 = v.x * inv, p1 = v.y * inv, p2 = v.z * inv, p3 = v.w * inv;
    ushort4 oh, ol;
    oh.x = f2bf(p0); ol.x = f2bf(p0 - bf2f(oh.x));
    oh.y = f2bf(p1); ol.y = f2bf(p1 - bf2f(oh.y));
    oh.z = f2bf(p2); ol.z = f2bf(p2 - bf2f(oh.z));
    oh.w = f2bf(p3); ol.w = f2bf(p3 - bf2f(oh.w));
    *(ushort4*)(Ph + base + t * 4) = oh;
    *(ushort4*)(Pl + base + t * 4) = ol;
}

// nearest grid_sample from token-major X [1024][512] -> padded HWC bf16 hi/lo
__global__ __launch_bounds__(256) void grid_sample_p(const float* __restrict__ X,
                                                     u16* __restrict__ Ph,
                                                     u16* __restrict__ Pl)
{
    int idx = blockIdx.x * 256 + threadIdx.x;
    if (idx >= 2500 * 512) return;
    int c = idx & 511;
    int p = idx >> 9;
    int i = p / 50, j = p - i * 50;
    float vy = -49.f + 2.f * i;
    float gy = (vy + 51.2f) / 102.4f * 2.f - 1.f;
    float fy = ((gy + 1.f) * 32.f - 1.f) * 0.5f;
    int iy = (int)roundf(fy);
    bool oky = (iy >= 0) && (iy < 32);
    iy = min(max(iy, 0), 31);
    float vx = -49.f + 2.f * j;
    float gx = (vx + 51.2f) / 102.4f * 2.f - 1.f;
    float fx = ((gx + 1.f) * 32.f - 1.f) * 0.5f;
    int ix = (int)roundf(fx);
    bool okx = (ix >= 0) && (ix < 32);
    ix = min(max(ix, 0), 31);
    int tok = iy * 32 + ix;
    float v = (oky && okx) ? X[(long)tok * 512 + c] : 0.f;
    long po = ((long)(i + 1) * 52 + (j + 1)) * 512 + c;
    u16 h = f2bf(v);
    Ph[po] = h;
    Pl[po] = f2bf(v - bf2f(h));
}

// pixel shuffle r=2: UPF HWC [2500][2048] -> padded HWC bf16 hi/lo (102x102x512)
__global__ __launch_bounds__(256) void pixshuf_p(const float* __restrict__ up,
                                                 u16* __restrict__ Ph,
                                                 u16* __restrict__ Pl)
{
    int idx = blockIdx.x * 256 + threadIdx.x;
    if (idx >= 10000 * 512) return;
    int c = idx & 511;
    int p = idx >> 9;
    int oh = p / 100, ow = p - oh * 100;
    int h = oh >> 1, r1 = oh & 1, w2 = ow >> 1, r2 = ow & 1;
    float v = up[(long)(h * 50 + w2) * 2048 + (c << 2) + (r1 << 1) + r2];
    long po = ((long)(oh + 1) * 102 + (ow + 1)) * 512 + c;
    u16 hh = f2bf(v);
    Ph[po] = hh;
    Pl[po] = f2bf(v - bf2f(hh));
}

__global__ __launch_bounds__(256) void bnprep(
    const float* g1, const float* b1, const float* m1, const float* v1,
    const float* g2, const float* b2, const float* m2, const float* v2,
    float* sc1, float* bi1, float* sc2, float* bi2)
{
    int c = blockIdx.x * 256 + threadIdx.x;
    if (c >= 512) return;
    float s1 = g1[c] * rsqrtf(v1[c] + 1e-5f);
    sc1[c] = s1; bi1[c] = b1[c] - m1[c] * s1;
    float s2 = g2[c] * rsqrtf(v2[c] + 1e-5f);
    sc2[c] = s2; bi2[c] = b2[c] - m2[c] * s2;
}

// 1x1 conv (512->6) + sigmoid from HWC f32; one wave per pixel
__global__ __launch_bounds__(256) void conv1x1_sig_h(const float* __restrict__ in,
                                                     const float* __restrict__ w,
                                                     const float* __restrict__ b,
                                                     float* __restrict__ out)
{
    int pix = blockIdx.x * 4 + (threadIdx.x >> 6);
    int lane = threadIdx.x & 63;
    const float* row = in + (long)pix * 512;
    float4 a0 = *(const float4*)(row + lane * 8);
    float4 a1 = *(const float4*)(row + lane * 8 + 4);
    float s[6];
    #pragma unroll
    for (int co = 0; co < 6; ++co) {
        const float* wr = w + co * 512 + lane * 8;
        float4 w0 = *(const float4*)wr;
        float4 w1 = *(const float4*)(wr + 4);
        s[co] = a0.x * w0.x + a0.y * w0.y + a0.z * w0.z + a0.w * w0.w
              + a1.x * w1.x + a1.y * w1.y + a1.z * w1.z + a1.w * w1.w;
    }
    #pragma unroll
    for (int co = 0; co < 6; ++co)
        #pragma unroll
        for (int o = 32; o > 0; o >>= 1) s[co] += __shfl_xor(s[co], o);
    if (lane < 6) {
        float t = s[lane] + b[lane];
        out[lane * 10000 + pix] = 1.f / (1.f + expf(-t));
    }
}

// ---------------------------------------------------------------------------
extern "C" void kernel_launch(void* const* d_in, const int* in_sizes, int n_in,
                              void* d_out, int out_size, void* d_ws, size_t ws_size,
                              hipStream_t stream)
{
    const float* x      = (const float*)d_in[0];
    const float* qkv_w  = (const float*)d_in[1];
    const float* proj_w = (const float*)d_in[2];
    const float* proj_b = (const float*)d_in[3];
    const float* head_w = (const float*)d_in[4];
    const float* head_b = (const float*)d_in[5];
    const float* body_w = (const float*)d_in[6];
    const float* body_b = (const float*)d_in[7];
    const float* btail_w= (const float*)d_in[8];
    const float* btail_b= (const float*)d_in[9];
    const float* up_w   = (const float*)d_in[10];
    const float* up_b   = (const float*)d_in[11];
    const float* tail_w = (const float*)d_in[12];
    const float* tail_b = (const float*)d_in[13];
    const float* c1_w   = (const float*)d_in[14];
    const float* bn1_g  = (const float*)d_in[15];
    const float* bn1_b  = (const float*)d_in[16];
    const float* bn1_m  = (const float*)d_in[17];
    const float* bn1_v  = (const float*)d_in[18];
    const float* c2_w   = (const float*)d_in[19];
    const float* bn2_g  = (const float*)d_in[20];
    const float* bn2_b  = (const float*)d_in[21];
    const float* bn2_m  = (const float*)d_in[22];
    const float* bn2_v  = (const float*)d_in[23];
    const float* c3_w   = (const float*)d_in[24];
    const float* c3_b   = (const float*)d_in[25];

    char* base = (char*)d_ws;
    // ---- Phase A (attention) arena — unchanged offsets ----
    float*          S    = (float*)(base + 0);                 // 8x1024x1024 f32
    u16*            P_h  = (u16*)(base + 33554432);
    u16*            P_l  = (u16*)(base + 50331648);
    u16*            Q_h  = (u16*)(base + 67108864);            // 1024x1536
    u16*            Q_l  = (u16*)(base + 70254592);
    u16*            VT_h = (u16*)(base + 73400320);            // 512x1024
    u16*            VT_l = (u16*)(base + 74448896);
    u16*            qw_h = (u16*)(base + 75497472);            // 8x1536x512
    u16*            qw_l = (u16*)(base + 88080384);
    u16*            pw_h = (u16*)(base + 100663296);           // 8x512x512
    u16*            pw_l = (u16*)(base + 104857600);
    u16*            O_h  = (u16*)(base + 109051904);           // 1024x512
    u16*            O_l  = (u16*)(base + 110100480);
    float*          X32b = (float*)(base + 111149056);         // 1024x512 f32
    u16*            X_h  = (u16*)(base + 113246208);
    u16*            X_l  = (u16*)(base + 114294784);
    float*          X32a = (float*)(base + 115343360);         // survives to grid_sample
    // ---- Phase B (conv) arena — reuses Phase A scratch (all writes post-attn) ----
    u16*   WB_h = (u16*)(base + 0);                  // reordered weights, <=2048x4608
    u16*   WB_l = (u16*)(base + 18874368);
    u16*   PX_h = (u16*)(base + 37748736);           // padded 52x52x512 bf16 each
    u16*   PX_l = (u16*)(base + 40517632);
    u16*   PA_h = (u16*)(base + 43286528);
    u16*   PA_l = (u16*)(base + 46055424);
    u16*   PB_h = (u16*)(base + 48824320);
    u16*   PB_l = (u16*)(base + 51593216);           // 50x50 pads end @54362112
    float* HhF  = (float*)(base + 54362112);         // 2500x512 f32 HWC
    float* RF1  = (float*)(base + 59482112);
    float* RF2  = (float*)(base + 64602112);
    float* Cp   = (float*)(base + 69722112);         // split-K partials 3x2500x512 (50x50)
    float* Cp2  = (float*)(base + 37748736);         // split-K partials 2x10000x512 (100x100)
                                                     // overlaps PX/PA/PB + HhF/RF (dead post-pixshuf)
    float* UPF  = (float*)(base + 85082112);         // 2500x2048 f32 HWC
    float* Z2F  = (float*)(base + 85082112);         // alias (UPF dead after pixshuf)
    u16*   PU_h = (u16*)(base + 105562112);          // padded 102x102x512 bf16 each
    u16*   PU_l = (u16*)(base + 116215808);
    u16*   PY_h = (u16*)(base + 126869504);
    u16*   PY_l = (u16*)(base + 137523200);          // 100x100 pads end @148176896
    float* SC1  = (float*)(base + 151494656);
    float* BI1  = SC1 + 512;
    float* SC2  = BI1 + 512;
    float* BI2  = SC2 + 512;

    const float scale = 0.044194173824159216f;  // 512^-0.5

    // ---- prep ----
    xpose_cast2<<<dim3(48, 16, 8), 256, 0, stream>>>(qkv_w, qw_h, qw_l, 512, 1536);
    xpose_cast2<<<dim3(16, 16, 8), 256, 0, stream>>>(proj_w, pw_h, pw_l, 512, 512);
    xpose_x2<<<dim3(32, 16), 256, 0, stream>>>(x, X32a, X_h, X_l);

    // ---- 8 self-attention blocks ----
    for (int i = 0; i < 8; ++i) {
        float* Xold = (i % 2 == 0) ? X32a : X32b;
        float* Xnew = (i % 2 == 0) ? X32b : X32a;
        // qkv: [1024][1536] hi/lo   (64x64 tiles: 384 blocks)
        gemm3_nt<64, 64, 1, 4><<<dim3(24, 16, 1), 256, 0, stream>>>(
            X_h, X_l, 512, 0, qw_h + (long long)i * 786432, qw_l + (long long)i * 786432, 512, 0,
            nullptr, Q_h, Q_l, 1536, 0, nullptr, 1024, 1536, 512, 1.f,
            nullptr, nullptr, nullptr, 0);
        // scores per head -> S f32   (512 blocks, 2-resident)
        gemm3_nt<128, 128, 2, 2><<<dim3(8, 8, 8), 256, 0, stream>>>(
            Q_h, Q_l, 1536, 64, Q_h + 512, Q_l + 512, 1536, 64,
            S, nullptr, nullptr, 1024, 1048576, nullptr, 1024, 1024, 64, scale,
            nullptr, nullptr, nullptr, 0);
        softmax_bf2<<<8192, 256, 0, stream>>>(S, P_h, P_l);
        vt_xpose2<<<dim3(16, 32), 256, 0, stream>>>(Q_h, Q_l, VT_h, VT_l);
        // PV -> O hi/lo [1024][512]
        gemm3_nt<64, 64, 1, 4><<<dim3(1, 16, 8), 256, 0, stream>>>(
            P_h, P_l, 1024, 1048576, VT_h, VT_l, 1024, 65536,
            nullptr, O_h, O_l, 512, 64, nullptr, 1024, 64, 1024, 1.f,
            nullptr, nullptr, nullptr, 0);
        // proj + residual -> Xnew f32 + X hi/lo bf16
        gemm3_nt<64, 64, 1, 4><<<dim3(8, 16, 1), 256, 0, stream>>>(
            O_h, O_l, 512, 0, pw_h + (long long)i * 262144, pw_l + (long long)i * 262144, 512, 0,
            Xnew, X_h, X_l, 512, 0, Xold, 1024, 512, 512, 1.f,
            nullptr, nullptr, proj_b + i * 512, 0);
    }
    // final X in X32a (layer 7 writes X32a)

    // ---- zero padded 50x50 buffers (one contiguous span), then grid sample ----
    zero_f4<<<DIV_UP(1038336, 256), 256, 0, stream>>>((float4*)(base + 37748736), 1038336);
    grid_sample_p<<<DIV_UP(1280000, 256), 256, 0, stream>>>(X32a, PX_h, PX_l);
    // X32a now dead -> zero the padded 100x100 span (overlaps X32a)
    zero_f4<<<DIV_UP(2663424, 256), 256, 0, stream>>>((float4*)(base + 105562112), 2663424);

    // ---- implicit-GEMM conv3x3 (round-4 geometry + XCD-locality swizzle) ----
    auto convK = [&](const u16* iPh, const u16* iPl, int H, int Wd,
                     const float* wsrc, int Cout, const float* bias, const float* scl,
                     const float* resid, int relu,
                     float* outC, u16* oPh, u16* oPl) {
        int pW = Wd + 2, M = H * Wd;
        int tot = Cout * 4608;
        wreorder<<<DIV_UP(tot, 256), 256, 0, stream>>>(wsrc, WB_h, WB_l, tot);
        if (Cout == 512 && M == 2500) {
            // 50x50: split-K (z=3): 8x20x3 = 480 blocks, then fused reduce+epilogue
            conv_gemm<128, 64, 2, 2><<<dim3(8, DIV_UP(M, 128), 3), 256, 0, stream>>>(
                iPh, iPl, WB_h, WB_l, Wd, pW, M, 512, 1536, Cp,
                nullptr, nullptr, nullptr, nullptr, nullptr, nullptr, 0);
            reduce_ep<<<DIV_UP(M * 512 / 4, 256), 256, 0, stream>>>(
                Cp, 3, M, 512, Wd, pW, outC, oPh, oPl, resid, bias, scl, relu);
        } else if (Cout == 512) {
            // 100x100: split-K (z=2): 4x79x2 = 632 blocks (2 resident/CU), fused reduce
            conv_gemm<128, 128, 2, 2><<<dim3(4, DIV_UP(M, 128), 2), 256, 0, stream>>>(
                iPh, iPl, WB_h, WB_l, Wd, pW, M, 512, 2304, Cp2,
                nullptr, nullptr, nullptr, nullptr, nullptr, nullptr, 0);
            reduce_ep<<<DIV_UP(M * 512 / 4, 256), 256, 0, stream>>>(
                Cp2, 2, M, 512, Wd, pW, outC, oPh, oPl, resid, bias, scl, relu);
        } else {
            // up-conv 2048-out @50x50: 128x64 tiles -> 32x20 = 640 blocks (3 resident/CU)
            conv_gemm<128, 64, 2, 2><<<dim3(32, DIV_UP(M, 128), 1), 256, 0, stream>>>(
                iPh, iPl, WB_h, WB_l, Wd, pW, M, 2048, 4608, nullptr,
                outC, oPh, oPl, resid, bias, scl, relu);
        }
    };

    // EDSR head
    convK(PX_h, PX_l, 50, 50, head_w, 512, head_b, nullptr, nullptr, 0, HhF, PA_h, PA_l);
    // body resblocks
    const float* rres = HhF;
    float* RFs[2] = {RF1, RF2};
    for (int i = 0; i < 8; ++i) {
        convK(PA_h, PA_l, 50, 50, body_w + (long long)(2 * i) * 2359296, 512,
              body_b + 2 * i * 512, nullptr, nullptr, 1, nullptr, PB_h, PB_l);
        float* Rout = RFs[i & 1];
        convK(PB_h, PB_l, 50, 50, body_w + (long long)(2 * i + 1) * 2359296, 512,
              body_b + (2 * i + 1) * 512, nullptr, rres, 0, Rout, PA_h, PA_l);
        rres = Rout;
    }
    // body tail + skip
    convK(PA_h, PA_l, 50, 50, btail_w, 512, btail_b, nullptr, HhF, 0, nullptr, PB_h, PB_l);
    // upsample conv (512 -> 2048) to HWC f32
    convK(PB_h, PB_l, 50, 50, up_w, 2048, up_b, nullptr, nullptr, 0, UPF, nullptr, nullptr);
    pixshuf_p<<<DIV_UP(5120000, 256), 256, 0, stream>>>(UPF, PU_h, PU_l);
    // tail conv @100x100  (PX/PA/PB + HhF/RF now dead -> Cp2 region free)
    convK(PU_h, PU_l, 100, 100, tail_w, 512, tail_b, nullptr, nullptr, 0, nullptr, PY_h, PY_l);

    // classifier
    bnprep<<<2, 256, 0, stream>>>(bn1_g, bn1_b, bn1_m, bn1_v,
                                  bn2_g, bn2_b, bn2_m, bn2_v, SC1, BI1, SC2, BI2);
    convK(PY_h, PY_l, 100, 100, c1_w, 512, BI1, SC1, nullptr, 1, nullptr, PU_h, PU_l);
    convK(PU_h, PU_l, 100, 100, c2_w, 512, BI2, SC2, nullptr, 1, Z2F, nullptr, nullptr);
    conv1x1_sig_h<<<2500, 256, 0, stream>>>(Z2F, c3_w, c3_b, (float*)d_out);
}